// Round 1
// baseline (16160.838 us; speedup 1.0000x reference)
//
#include <hip/hip_runtime.h>

#define DIM 64

// Grid-stride float4 zero fill.
__global__ void zero_f4(float* __restrict__ p, size_t n4) {
    size_t i = (size_t)blockIdx.x * blockDim.x + threadIdx.x;
    size_t stride = (size_t)gridDim.x * blockDim.x;
    float4 z = make_float4(0.f, 0.f, 0.f, 0.f);
    for (; i < n4; i += stride)
        reinterpret_cast<float4*>(p)[i] = z;
}

// COO SpMM scatter: y[row[e]] += val[e] * x[col[e]], x given as two
// contiguous pieces p0 (rows [0,split)) and p1 (rows [split,N)).
// 16 threads per edge, 4 dims per thread (float4).
__global__ void spmm_atomic(const float* __restrict__ val,
                            const int* __restrict__ row,
                            const int* __restrict__ col,
                            const float* __restrict__ p0,
                            const float* __restrict__ p1,
                            int split,
                            float* __restrict__ y,
                            int nedges) {
    long long t = (long long)blockIdx.x * blockDim.x + threadIdx.x;
    int e = (int)(t >> 4);
    if (e >= nedges) return;
    int d = ((int)t & 15) << 2;

    float v = val[e];
    int r = row[e];
    int c = col[e];

    const float* src = (c < split) ? (p0 + (size_t)c * DIM)
                                   : (p1 + (size_t)(c - split) * DIM);
    float4 xv = *reinterpret_cast<const float4*>(src + d);

    float* o = y + (size_t)r * DIM + d;
    unsafeAtomicAdd(o + 0, v * xv.x);
    unsafeAtomicAdd(o + 1, v * xv.y);
    unsafeAtomicAdd(o + 2, v * xv.z);
    unsafeAtomicAdd(o + 3, v * xv.w);
}

extern "C" void kernel_launch(void* const* d_in, const int* in_sizes, int n_in,
                              void* d_out, int out_size, void* d_ws, size_t ws_size,
                              hipStream_t stream) {
    const float* user = (const float*)d_in[0];
    const float* item = (const float*)d_in[1];
    const float* val  = (const float*)d_in[2];
    const int*   row  = (const int*)d_in[3];
    const int*   col  = (const int*)d_in[4];

    int nU = in_sizes[0] / DIM;
    int nI = in_sizes[1] / DIM;
    int nE = in_sizes[2];
    size_t nNodes   = (size_t)nU + (size_t)nI;
    size_t bufElems = nNodes * DIM;       // 9.6M floats = 38.4 MB
    size_t n4       = bufElems / 4;

    float* X = (float*)d_ws;    // ping buffer (38.4 MB of d_ws)
    float* Y = (float*)d_out;   // pong buffer == final output

    int  zthreads = 256;
    int  zblocks  = (int)((n4 + zthreads - 1) / zthreads);
    if (zblocks > 4096) zblocks = 4096;

    long long totalThreads = (long long)nE * 16;
    dim3 sgrid((unsigned)((totalThreads + 255) / 256));
    dim3 sblock(256);

    const float* Xu = X;
    const float* Xi = X + (size_t)nU * DIM;
    const float* Yu = Y;
    const float* Yi = Y + (size_t)nU * DIM;

    // layer 1: (user|item) -> X
    zero_f4<<<zblocks, zthreads, 0, stream>>>(X, n4);
    spmm_atomic<<<sgrid, sblock, 0, stream>>>(val, row, col, user, item, nU, X, nE);

    // layer 2: X -> Y
    zero_f4<<<zblocks, zthreads, 0, stream>>>(Y, n4);
    spmm_atomic<<<sgrid, sblock, 0, stream>>>(val, row, col, Xu, Xi, nU, Y, nE);

    // layer 3: Y -> X
    zero_f4<<<zblocks, zthreads, 0, stream>>>(X, n4);
    spmm_atomic<<<sgrid, sblock, 0, stream>>>(val, row, col, Yu, Yi, nU, X, nE);

    // layer 4: X -> Y (= d_out)
    zero_f4<<<zblocks, zthreads, 0, stream>>>(Y, n4);
    spmm_atomic<<<sgrid, sblock, 0, stream>>>(val, row, col, Xu, Xi, nU, Y, nE);
}

// Round 2
// 1584.902 us; speedup vs baseline: 10.1967x; 10.1967x over previous
//
#include <hip/hip_runtime.h>

#define DIM 64
#define SB 256   // scan block size

// ---------------- utility: zero ints ----------------
__global__ void zero_i(int* __restrict__ p, int n) {
    int i = blockIdx.x * blockDim.x + threadIdx.x;
    int stride = gridDim.x * blockDim.x;
    for (; i < n; i += stride) p[i] = 0;
}

__global__ void zero_f4(float* __restrict__ p, size_t n4) {
    size_t i = (size_t)blockIdx.x * blockDim.x + threadIdx.x;
    size_t stride = (size_t)gridDim.x * blockDim.x;
    float4 z = make_float4(0.f, 0.f, 0.f, 0.f);
    for (; i < n4; i += stride)
        reinterpret_cast<float4*>(p)[i] = z;
}

// ---------------- CSR build ----------------
__global__ void hist_rows(const int* __restrict__ row, int* __restrict__ counts, int ne) {
    int e = blockIdx.x * blockDim.x + threadIdx.x;
    if (e < ne) atomicAdd(&counts[row[e]], 1);
}

// inclusive scan within blocks of SB, block sums to partials
__global__ void scan_block(const int* __restrict__ counts, int* __restrict__ tmp,
                           int* __restrict__ partials, int n) {
    __shared__ int s[SB];
    int i = blockIdx.x * SB + threadIdx.x;
    int v = (i < n) ? counts[i] : 0;
    s[threadIdx.x] = v;
    __syncthreads();
    for (int off = 1; off < SB; off <<= 1) {
        int a = (threadIdx.x >= off) ? s[threadIdx.x - off] : 0;
        __syncthreads();
        s[threadIdx.x] += a;
        __syncthreads();
    }
    if (i < n) tmp[i] = s[threadIdx.x];
    if (threadIdx.x == SB - 1) partials[blockIdx.x] = s[SB - 1];
}

// single-block exclusive scan of partials (nb <= 1024)
__global__ void scan_partials(int* __restrict__ partials, int nb) {
    __shared__ int s[1024];
    int t = threadIdx.x;
    int v = (t < nb) ? partials[t] : 0;
    s[t] = v;
    __syncthreads();
    for (int off = 1; off < 1024; off <<= 1) {
        int a = (t >= off) ? s[t - off] : 0;
        __syncthreads();
        s[t] += a;
        __syncthreads();
    }
    if (t < nb) partials[t] = (t == 0) ? 0 : s[t - 1];
}

__global__ void finalize_rowptr(const int* __restrict__ tmp, const int* __restrict__ partials,
                                int* __restrict__ rowptr, int n) {
    int i = blockIdx.x * blockDim.x + threadIdx.x;
    if (i < n) rowptr[i + 1] = tmp[i] + partials[i / SB];
    if (i == 0) rowptr[0] = 0;
}

// scatter edges into CSR order, packed {col, val_bits}
__global__ void scatter_edges(const int* __restrict__ row, const int* __restrict__ col,
                              const float* __restrict__ val, const int* __restrict__ rowptr,
                              int* __restrict__ cursor, int2* __restrict__ colval, int ne) {
    int e = blockIdx.x * blockDim.x + threadIdx.x;
    if (e < ne) {
        int r = row[e];
        int pos = rowptr[r] + atomicAdd(&cursor[r], 1);
        colval[pos] = make_int2(col[e], __float_as_int(val[e]));
    }
}

// ---------------- CSR SpMM: one wave per row, lane = dim ----------------
__global__ __launch_bounds__(256) void spmm_csr(const int2* __restrict__ colval,
                                                const int* __restrict__ rowptr,
                                                const float* __restrict__ p0,
                                                const float* __restrict__ p1,
                                                int split,
                                                float* __restrict__ y,
                                                int nrows) {
    int wid = (int)(((size_t)blockIdx.x * blockDim.x + threadIdx.x) >> 6);
    int lane = threadIdx.x & 63;
    if (wid >= nrows) return;

    int beg = rowptr[wid];
    int end = rowptr[wid + 1];

    float acc0 = 0.f, acc1 = 0.f;
    int e = beg;
    for (; e + 1 < end; e += 2) {
        int2 cv0 = colval[e];
        int2 cv1 = colval[e + 1];
        const float* s0 = (cv0.x < split) ? (p0 + (size_t)cv0.x * DIM)
                                          : (p1 + (size_t)(cv0.x - split) * DIM);
        const float* s1 = (cv1.x < split) ? (p0 + (size_t)cv1.x * DIM)
                                          : (p1 + (size_t)(cv1.x - split) * DIM);
        float x0 = s0[lane];
        float x1 = s1[lane];
        acc0 = fmaf(__int_as_float(cv0.y), x0, acc0);
        acc1 = fmaf(__int_as_float(cv1.y), x1, acc1);
    }
    if (e < end) {
        int2 cv = colval[e];
        const float* s = (cv.x < split) ? (p0 + (size_t)cv.x * DIM)
                                        : (p1 + (size_t)(cv.x - split) * DIM);
        acc0 = fmaf(__int_as_float(cv.y), s[lane], acc0);
    }
    y[(size_t)wid * DIM + lane] = acc0 + acc1;
}

// ---------------- fallback: atomic scatter (round-1 path) ----------------
__global__ void spmm_atomic(const float* __restrict__ val,
                            const int* __restrict__ row,
                            const int* __restrict__ col,
                            const float* __restrict__ p0,
                            const float* __restrict__ p1,
                            int split,
                            float* __restrict__ y,
                            int nedges) {
    long long t = (long long)blockIdx.x * blockDim.x + threadIdx.x;
    int e = (int)(t >> 4);
    if (e >= nedges) return;
    int d = ((int)t & 15) << 2;
    float v = val[e];
    int r = row[e];
    int c = col[e];
    const float* src = (c < split) ? (p0 + (size_t)c * DIM)
                                   : (p1 + (size_t)(c - split) * DIM);
    float4 xv = *reinterpret_cast<const float4*>(src + d);
    float* o = y + (size_t)r * DIM + d;
    unsafeAtomicAdd(o + 0, v * xv.x);
    unsafeAtomicAdd(o + 1, v * xv.y);
    unsafeAtomicAdd(o + 2, v * xv.z);
    unsafeAtomicAdd(o + 3, v * xv.w);
}

extern "C" void kernel_launch(void* const* d_in, const int* in_sizes, int n_in,
                              void* d_out, int out_size, void* d_ws, size_t ws_size,
                              hipStream_t stream) {
    const float* user = (const float*)d_in[0];
    const float* item = (const float*)d_in[1];
    const float* val  = (const float*)d_in[2];
    const int*   row  = (const int*)d_in[3];
    const int*   col  = (const int*)d_in[4];

    int nU = in_sizes[0] / DIM;
    int nI = in_sizes[1] / DIM;
    int nE = in_sizes[2];
    int nN = nU + nI;
    size_t bufElems = (size_t)nN * DIM;
    size_t n4 = bufElems / 4;

    // ---- workspace carve-up (256B aligned) ----
    char* base = (char*)d_ws;
    size_t off = 0;
    auto alloc = [&](size_t bytes) -> void* {
        void* p = base + off;
        off = (off + bytes + 255) & ~(size_t)255;
        return p;
    };
    float* X       = (float*)alloc(bufElems * sizeof(float));       // ping buffer
    int2*  colval  = (int2*)alloc((size_t)nE * sizeof(int2));       // CSR packed edges
    int*   rowptr  = (int*)alloc((size_t)(nN + 1) * sizeof(int));
    int*   counts  = (int*)alloc((size_t)nN * sizeof(int));         // also cursor
    int*   tmp     = (int*)alloc((size_t)nN * sizeof(int));
    int*   partials= (int*)alloc(1024 * sizeof(int));
    size_t needed  = off;

    float* Y = (float*)d_out;

    int nScanBlocks = (nN + SB - 1) / SB;   // 586 for 150000 — fits one 1024-block pass

    if (ws_size >= needed && nScanBlocks <= 1024) {
        // ---- build CSR (once, amortized over 4 layers) ----
        int eb = (nE + 255) / 256;
        int nb = (nN + 255) / 256;
        zero_i<<<256, 256, 0, stream>>>(counts, nN);
        hist_rows<<<eb, 256, 0, stream>>>(row, counts, nE);
        scan_block<<<nScanBlocks, SB, 0, stream>>>(counts, tmp, partials, nN);
        scan_partials<<<1, 1024, 0, stream>>>(partials, nScanBlocks);
        finalize_rowptr<<<nb, 256, 0, stream>>>(tmp, partials, rowptr, nN);
        zero_i<<<256, 256, 0, stream>>>(counts, nN);  // reuse as cursor
        scatter_edges<<<eb, 256, 0, stream>>>(row, col, val, rowptr, counts, colval, nE);

        // ---- 4 propagation layers, no atomics, every row fully written ----
        int sgrid = (int)(((size_t)nN * 64 + 255) / 256);
        // layer 1: (user|item) -> X
        spmm_csr<<<sgrid, 256, 0, stream>>>(colval, rowptr, user, item, nU, X, nN);
        // layer 2: X -> Y
        spmm_csr<<<sgrid, 256, 0, stream>>>(colval, rowptr, X, X + (size_t)nU * DIM, nU, Y, nN);
        // layer 3: Y -> X
        spmm_csr<<<sgrid, 256, 0, stream>>>(colval, rowptr, Y, Y + (size_t)nU * DIM, nU, X, nN);
        // layer 4: X -> Y (= d_out)
        spmm_csr<<<sgrid, 256, 0, stream>>>(colval, rowptr, X, X + (size_t)nU * DIM, nU, Y, nN);
    } else {
        // ---- fallback: atomic path (only needs X) ----
        int zblocks = (int)((n4 + 255) / 256);
        if (zblocks > 4096) zblocks = 4096;
        long long totalThreads = (long long)nE * 16;
        dim3 sgrid((unsigned)((totalThreads + 255) / 256));
        const float* Xu = X;
        const float* Xi = X + (size_t)nU * DIM;
        const float* Yu = Y;
        const float* Yi = Y + (size_t)nU * DIM;
        zero_f4<<<zblocks, 256, 0, stream>>>(X, n4);
        spmm_atomic<<<sgrid, 256, 0, stream>>>(val, row, col, user, item, nU, X, nE);
        zero_f4<<<zblocks, 256, 0, stream>>>(Y, n4);
        spmm_atomic<<<sgrid, 256, 0, stream>>>(val, row, col, Xu, Xi, nU, Y, nE);
        zero_f4<<<zblocks, 256, 0, stream>>>(X, n4);
        spmm_atomic<<<sgrid, 256, 0, stream>>>(val, row, col, Yu, Yi, nU, X, nE);
        zero_f4<<<zblocks, 256, 0, stream>>>(Y, n4);
        spmm_atomic<<<sgrid, 256, 0, stream>>>(val, row, col, Xu, Xi, nU, Y, nE);
    }
}

// Round 3
// 919.016 us; speedup vs baseline: 17.5849x; 1.7246x over previous
//
#include <hip/hip_runtime.h>

#define DIM 64
#define SB 256   // scan block size

// ---------------- utility ----------------
__global__ void zero_i(int* __restrict__ p, int n) {
    int i = blockIdx.x * blockDim.x + threadIdx.x;
    int stride = gridDim.x * blockDim.x;
    for (; i < n; i += stride) p[i] = 0;
}

__global__ void zero_f4(float* __restrict__ p, size_t n4) {
    size_t i = (size_t)blockIdx.x * blockDim.x + threadIdx.x;
    size_t stride = (size_t)gridDim.x * blockDim.x;
    float4 z = make_float4(0.f, 0.f, 0.f, 0.f);
    for (; i < n4; i += stride)
        reinterpret_cast<float4*>(p)[i] = z;
}

// ---------------- CSR build ----------------
// histogram + per-edge rank in one pass (rank = old count)
__global__ void hist_rank(const int* __restrict__ row, int* __restrict__ counts,
                          int* __restrict__ rank, int ne) {
    int e = blockIdx.x * blockDim.x + threadIdx.x;
    if (e < ne) rank[e] = atomicAdd(&counts[row[e]], 1);
}

// inclusive scan within blocks of SB, block sums to partials
__global__ void scan_block(const int* __restrict__ counts, int* __restrict__ tmp,
                           int* __restrict__ partials, int n) {
    __shared__ int s[SB];
    int i = blockIdx.x * SB + threadIdx.x;
    int v = (i < n) ? counts[i] : 0;
    s[threadIdx.x] = v;
    __syncthreads();
    for (int off = 1; off < SB; off <<= 1) {
        int a = (threadIdx.x >= off) ? s[threadIdx.x - off] : 0;
        __syncthreads();
        s[threadIdx.x] += a;
        __syncthreads();
    }
    if (i < n) tmp[i] = s[threadIdx.x];
    if (threadIdx.x == SB - 1) partials[blockIdx.x] = s[SB - 1];
}

// single-block exclusive scan of partials (nb <= 1024)
__global__ void scan_partials(int* __restrict__ partials, int nb) {
    __shared__ int s[1024];
    int t = threadIdx.x;
    int v = (t < nb) ? partials[t] : 0;
    s[t] = v;
    __syncthreads();
    for (int off = 1; off < 1024; off <<= 1) {
        int a = (t >= off) ? s[t - off] : 0;
        __syncthreads();
        s[t] += a;
        __syncthreads();
    }
    if (t < nb) partials[t] = (t == 0) ? 0 : s[t - 1];
}

__global__ void finalize_rowptr(const int* __restrict__ tmp, const int* __restrict__ partials,
                                int* __restrict__ rowptr, int n) {
    int i = blockIdx.x * blockDim.x + threadIdx.x;
    if (i < n) rowptr[i + 1] = tmp[i] + partials[i / SB];
    if (i == 0) rowptr[0] = 0;
}

// scatter edges into CSR order using precomputed rank (no atomics)
__global__ void scatter_edges(const int* __restrict__ row, const int* __restrict__ col,
                              const float* __restrict__ val, const int* __restrict__ rowptr,
                              const int* __restrict__ rank, int2* __restrict__ colval, int ne) {
    int e = blockIdx.x * blockDim.x + threadIdx.x;
    if (e < ne) {
        int r = row[e];
        int pos = rowptr[r] + rank[e];
        colval[pos] = make_int2(col[e], __float_as_int(val[e]));
    }
}

// ---------------- CSR SpMM v2: one wave per row, 4 edges x 16 lanes x float4 ----------------
__global__ __launch_bounds__(256) void spmm_csr(const int2* __restrict__ colval,
                                                const int* __restrict__ rowptr,
                                                const float* __restrict__ p0,
                                                const float* __restrict__ p1,
                                                int split,
                                                float* __restrict__ y,
                                                int nrows) {
    int wid  = (int)(((size_t)blockIdx.x * blockDim.x + threadIdx.x) >> 6);
    int lane = threadIdx.x & 63;
    if (wid >= nrows) return;
    int sub = lane >> 4;          // which of 4 edges in the group
    int q   = (lane & 15) << 2;   // dim quad: dims q..q+3

    int beg = rowptr[wid];
    int end = rowptr[wid + 1];
    int len = end - beg;
    int nfull = len >> 2;

    float4 acc = make_float4(0.f, 0.f, 0.f, 0.f);

    int e = beg + sub;
    #pragma unroll 2
    for (int g = 0; g < nfull; ++g, e += 4) {
        int2 cv = colval[e];
        float v = __int_as_float(cv.y);
        const float* s = (cv.x < split) ? (p0 + (size_t)cv.x * DIM)
                                        : (p1 + (size_t)(cv.x - split) * DIM);
        float4 xv = *reinterpret_cast<const float4*>(s + q);
        acc.x = fmaf(v, xv.x, acc.x);
        acc.y = fmaf(v, xv.y, acc.y);
        acc.z = fmaf(v, xv.z, acc.z);
        acc.w = fmaf(v, xv.w, acc.w);
    }
    int rem = len & 3;
    if (sub < rem) {
        int2 cv = colval[e];
        float v = __int_as_float(cv.y);
        const float* s = (cv.x < split) ? (p0 + (size_t)cv.x * DIM)
                                        : (p1 + (size_t)(cv.x - split) * DIM);
        float4 xv = *reinterpret_cast<const float4*>(s + q);
        acc.x = fmaf(v, xv.x, acc.x);
        acc.y = fmaf(v, xv.y, acc.y);
        acc.z = fmaf(v, xv.z, acc.z);
        acc.w = fmaf(v, xv.w, acc.w);
    }

    // reduce across the 4 sub-groups (lanes differing in bits 4,5)
    #pragma unroll
    for (int off = 16; off <= 32; off <<= 1) {
        acc.x += __shfl_xor(acc.x, off);
        acc.y += __shfl_xor(acc.y, off);
        acc.z += __shfl_xor(acc.z, off);
        acc.w += __shfl_xor(acc.w, off);
    }

    if (sub == 0)
        *reinterpret_cast<float4*>(y + (size_t)wid * DIM + q) = acc;
}

// ---------------- fallback: atomic scatter ----------------
__global__ void spmm_atomic(const float* __restrict__ val,
                            const int* __restrict__ row,
                            const int* __restrict__ col,
                            const float* __restrict__ p0,
                            const float* __restrict__ p1,
                            int split,
                            float* __restrict__ y,
                            int nedges) {
    long long t = (long long)blockIdx.x * blockDim.x + threadIdx.x;
    int e = (int)(t >> 4);
    if (e >= nedges) return;
    int d = ((int)t & 15) << 2;
    float v = val[e];
    int r = row[e];
    int c = col[e];
    const float* src = (c < split) ? (p0 + (size_t)c * DIM)
                                   : (p1 + (size_t)(c - split) * DIM);
    float4 xv = *reinterpret_cast<const float4*>(src + d);
    float* o = y + (size_t)r * DIM + d;
    unsafeAtomicAdd(o + 0, v * xv.x);
    unsafeAtomicAdd(o + 1, v * xv.y);
    unsafeAtomicAdd(o + 2, v * xv.z);
    unsafeAtomicAdd(o + 3, v * xv.w);
}

extern "C" void kernel_launch(void* const* d_in, const int* in_sizes, int n_in,
                              void* d_out, int out_size, void* d_ws, size_t ws_size,
                              hipStream_t stream) {
    const float* user = (const float*)d_in[0];
    const float* item = (const float*)d_in[1];
    const float* val  = (const float*)d_in[2];
    const int*   row  = (const int*)d_in[3];
    const int*   col  = (const int*)d_in[4];

    int nU = in_sizes[0] / DIM;
    int nI = in_sizes[1] / DIM;
    int nE = in_sizes[2];
    int nN = nU + nI;
    size_t bufElems = (size_t)nN * DIM;
    size_t n4 = bufElems / 4;

    // ---- workspace carve-up (256B aligned) ----
    char* base = (char*)d_ws;
    size_t off = 0;
    auto alloc = [&](size_t bytes) -> void* {
        void* p = base + off;
        off = (off + bytes + 255) & ~(size_t)255;
        return p;
    };
    float* X       = (float*)alloc(bufElems * sizeof(float));       // ping buffer
    int2*  colval  = (int2*)alloc((size_t)nE * sizeof(int2));       // CSR packed edges
    int*   rank    = (int*)alloc((size_t)nE * sizeof(int));         // per-edge rank
    int*   rowptr  = (int*)alloc((size_t)(nN + 1) * sizeof(int));
    int*   counts  = (int*)alloc((size_t)nN * sizeof(int));
    int*   tmp     = (int*)alloc((size_t)nN * sizeof(int));
    int*   partials= (int*)alloc(1024 * sizeof(int));
    size_t needed  = off;

    float* Y = (float*)d_out;

    int nScanBlocks = (nN + SB - 1) / SB;

    if (ws_size >= needed && nScanBlocks <= 1024) {
        // ---- build CSR ----
        int eb = (nE + 255) / 256;
        int nb = (nN + 255) / 256;
        zero_i<<<256, 256, 0, stream>>>(counts, nN);
        hist_rank<<<eb, 256, 0, stream>>>(row, counts, rank, nE);
        scan_block<<<nScanBlocks, SB, 0, stream>>>(counts, tmp, partials, nN);
        scan_partials<<<1, 1024, 0, stream>>>(partials, nScanBlocks);
        finalize_rowptr<<<nb, 256, 0, stream>>>(tmp, partials, rowptr, nN);
        scatter_edges<<<eb, 256, 0, stream>>>(row, col, val, rowptr, rank, colval, nE);

        // ---- 4 propagation layers ----
        int sgrid = (int)(((size_t)nN * 64 + 255) / 256);
        spmm_csr<<<sgrid, 256, 0, stream>>>(colval, rowptr, user, item, nU, X, nN);
        spmm_csr<<<sgrid, 256, 0, stream>>>(colval, rowptr, X, X + (size_t)nU * DIM, nU, Y, nN);
        spmm_csr<<<sgrid, 256, 0, stream>>>(colval, rowptr, Y, Y + (size_t)nU * DIM, nU, X, nN);
        spmm_csr<<<sgrid, 256, 0, stream>>>(colval, rowptr, X, X + (size_t)nU * DIM, nU, Y, nN);
    } else {
        // ---- fallback: atomic path ----
        int zblocks = (int)((n4 + 255) / 256);
        if (zblocks > 4096) zblocks = 4096;
        long long totalThreads = (long long)nE * 16;
        dim3 sgrid((unsigned)((totalThreads + 255) / 256));
        const float* Xu = X;
        const float* Xi = X + (size_t)nU * DIM;
        const float* Yu = Y;
        const float* Yi = Y + (size_t)nU * DIM;
        zero_f4<<<zblocks, 256, 0, stream>>>(X, n4);
        spmm_atomic<<<sgrid, 256, 0, stream>>>(val, row, col, user, item, nU, X, nE);
        zero_f4<<<zblocks, 256, 0, stream>>>(Y, n4);
        spmm_atomic<<<sgrid, 256, 0, stream>>>(val, row, col, Xu, Xi, nU, Y, nE);
        zero_f4<<<zblocks, 256, 0, stream>>>(X, n4);
        spmm_atomic<<<sgrid, 256, 0, stream>>>(val, row, col, Yu, Yi, nU, X, nE);
        zero_f4<<<zblocks, 256, 0, stream>>>(Y, n4);
        spmm_atomic<<<sgrid, 256, 0, stream>>>(val, row, col, Xu, Xi, nU, Y, nE);
    }
}